// Round 18
// baseline (233.607 us; speedup 1.0000x reference)
//
#include <hip/hip_runtime.h>
#include <hip/hip_bf16.h>
#include <stdint.h>

// Problem constants
#define NB 8
#define NC 256
#define NN 16384
#define KS 64        // gram k-split: 64 chunks of 256 (4 ktiles) -> 512 blocks

typedef short bf16x8 __attribute__((ext_vector_type(8)));  // 8 bf16 = 4 VGPR
typedef float f32x4  __attribute__((ext_vector_type(4)));
typedef uint32_t u32;

__device__ __forceinline__ unsigned short f2bf(float f) {
  union { float f; unsigned u; } c; c.f = f;
  return (unsigned short)((c.u + 0x7FFFu + ((c.u >> 16) & 1u)) >> 16);  // RNE
}
__device__ __forceinline__ float bf2f(unsigned short h) {
  union { unsigned u; float f; } c; c.u = ((unsigned)h) << 16;
  return c.f;
}
// pack float2 -> 2 bf16 in a u32 (RNE, same rounding as f2bf)
__device__ __forceinline__ u32 pk2(float a, float b) {
  union { __hip_bfloat162 h; u32 u; } c;
  c.h = __float22bfloat162_rn(make_float2(a, b));
  return c.u;
}

// async global->LDS, 16B per lane; LDS dest is wave-uniform base + lane*16
__device__ __forceinline__ void gload16(const void* g, void* l) {
  __builtin_amdgcn_global_load_lds(
      (const __attribute__((address_space(1))) u32*)g,
      (__attribute__((address_space(3))) u32*)l, 16, 0, 0);
}

// Stage a [128 rows x 64 bf16] tile (row stride ld_bytes) into 16KB of LDS.
// T2 XOR-swizzle applied on the per-lane global source; LDS stays linear.
__device__ __forceinline__ void stage_tile(const char* src, int ld_bytes,
                                           char* lds, int w, int l) {
#pragma unroll
  for (int i = 0; i < 4; ++i) {
    int s = (w * 4 + i) * 64 + l;      // 0..1023 : 16B chunk index
    int row = s >> 3;
    int srcslot = (l & 7) ^ (row & 7);
    gload16(src + (size_t)row * ld_bytes + srcslot * 16,
            lds + (w * 4 + i) * 1024);
  }
}

// ---- gramT v5: reg-staged bf16 tile; KS=64 -> 512 gram blocks (2/CU) -------
// blocks [0,512): gram, one (ks,b) each, disjoint K-chunks of 256 (4 ktiles).
// blocks [512,576): weight prep (4 rows per block).
__global__ __launch_bounds__(1024) void k_gramT(
    const float* __restrict__ x, unsigned short* __restrict__ gpart,
    char* __restrict__ xt,
    const float* __restrict__ wqkv, const float* __restrict__ wdw,
    float* __restrict__ Wcat, float* __restrict__ WkT,
    float* __restrict__ Wv2) {
  __shared__ __align__(16) unsigned short tile[256 * 72];  // 36 KB
  const int bid = blockIdx.x;
  const int tid = threadIdx.x;

  if (bid >= KS * NB) {
    // ---------------- prepw role ----------------
    const int r = (bid - KS * NB) * 4 + (tid >> 8);
    const int t = tid & 255;
    Wcat[r * 256 + t] = wqkv[r * 256 + t] * wdw[r];
    float kv = wqkv[(256 + r) * 256 + t] * wdw[256 + r];
    Wcat[65536 + r * 256 + t] = kv;
    WkT[t * 256 + r] = kv;
    Wv2[r * 256 + t] = wqkv[(512 + r) * 256 + t] * wdw[512 + r];
    return;
  }

  // ---------------- gram role ----------------
  const int ks = bid & (KS - 1), b = bid >> 6;
  const int w = tid >> 6, l = tid & 63;
  const int wm = w >> 2, wn = w & 3;           // 4m x 4n wave grid
  const int cg = tid >> 4, ng = tid & 15;      // staging: c0=cg*4, n0=ng*4
  const int c0 = cg * 4, n0 = ng * 4;
  f32x4 acc[4][4];
#pragma unroll
  for (int m = 0; m < 4; ++m)
#pragma unroll
    for (int n = 0; n < 4; ++n) acc[m][n] = (f32x4){0.f, 0.f, 0.f, 0.f};
  const float* x0 = x + (size_t)b * NC * NN + (size_t)ks * 256;

  float4 f[4];     // fp32 staging (one generation)
  u32 hw[4][2];    // bf16 staging: hw[j] = 4 bf16 of row c0+j, cols n0..n0+3

#define LOADS(kt)                                                           \
  {                                                                         \
    _Pragma("unroll") for (int j = 0; j < 4; ++j)                           \
        f[j] = *(const float4*)&x0[(size_t)(c0 + j) * NN + (kt) * 64 + n0]; \
  }
#define CVT()                                                               \
  {                                                                         \
    _Pragma("unroll") for (int j = 0; j < 4; ++j) {                         \
      hw[j][0] = pk2(f[j].x, f[j].y);                                       \
      hw[j][1] = pk2(f[j].z, f[j].w);                                       \
    }                                                                       \
  }
#define DSW()                                                               \
  {                                                                         \
    _Pragma("unroll") for (int j = 0; j < 4; ++j)                           \
        *(uint2*)&tile[(c0 + j) * 72 + n0] = make_uint2(hw[j][0], hw[j][1]);\
  }

  // prologue: tile 0
  LOADS(0); CVT(); DSW();
  __syncthreads();

  for (int kt = 0; kt < 4; ++kt) {
    if (kt < 3) LOADS(kt + 1);   // issue next loads; land in regs during MFMA
    // ---- MFMA from bf16 tile (one b128 read per fragment) ----
#pragma unroll
    for (int ks2 = 0; ks2 < 2; ++ks2) {
      const int ko = ks2 * 32 + (l >> 4) * 8;   // elem offset of lane's 8 bf16
      bf16x8 av[4], bv[4];
#pragma unroll
      for (int m = 0; m < 4; ++m) {
        int row = wm * 64 + m * 16 + (l & 15);
        av[m] = *(const bf16x8*)&tile[row * 72 + ko];
      }
#pragma unroll
      for (int n = 0; n < 4; ++n) {
        int row = wn * 64 + n * 16 + (l & 15);
        bv[n] = *(const bf16x8*)&tile[row * 72 + ko];
      }
#pragma unroll
      for (int m = 0; m < 4; ++m)
#pragma unroll
        for (int n = 0; n < 4; ++n)
          acc[m][n] = __builtin_amdgcn_mfma_f32_16x16x32_bf16(
              av[m], bv[n], acc[m][n], 0, 0, 0);
    }
    // ---- xt[b][n][c] straight from bf16 regs (4 n-rows, 4 c each) ----
    {
      const int gn = ks * 256 + kt * 64 + n0;
#pragma unroll
      for (int k = 0; k < 4; ++k) {
        u32 e0 = (k < 2) ? (hw[0][0] >> (16 * k)) : (hw[0][1] >> (16 * (k - 2)));
        u32 e1 = (k < 2) ? (hw[1][0] >> (16 * k)) : (hw[1][1] >> (16 * (k - 2)));
        u32 e2 = (k < 2) ? (hw[2][0] >> (16 * k)) : (hw[2][1] >> (16 * (k - 2)));
        u32 e3 = (k < 2) ? (hw[3][0] >> (16 * k)) : (hw[3][1] >> (16 * (k - 2)));
        uint2 ov = make_uint2((e0 & 0xffff) | (e1 << 16),
                              (e2 & 0xffff) | (e3 << 16));
        *(uint2*)(xt + (((size_t)b * NN + gn + k) * 256 + c0) * 2) = ov;
      }
    }
    __syncthreads();             // tile consumed; safe to overwrite
    if (kt < 3) {
      CVT();                     // vmcnt for LOADS(kt+1) waits here (hidden)
      DSW();
      __syncthreads();           // tile(kt+1) ready
    }
  }
#undef LOADS
#undef CVT
#undef DSW
  // ---- gpart epilogue (bf16) ----
  unsigned short* gp = gpart + ((size_t)(ks * NB + b)) * 65536;
#pragma unroll
  for (int m = 0; m < 4; ++m)
#pragma unroll
    for (int n = 0; n < 4; ++n)
#pragma unroll
      for (int r = 0; r < 4; ++r) {
        int c = wm * 64 + m * 16 + ((l >> 4) << 2) + r;
        int d = wn * 64 + n * 16 + (l & 15);
        gp[(size_t)c * 256 + d] = f2bf(acc[m][n][r]);
      }
}

// ---- G[b] = sum_ks gpart (bf16 in, fp32 out); grid (128, NB) ---------------
__global__ __launch_bounds__(256) void k_reduceG(
    const unsigned short* __restrict__ gpart, float* __restrict__ G) {
  const int t = threadIdx.x;
  const int c = blockIdx.x * 2 + (t >> 7), b = blockIdx.y;
  const int d0 = (t & 127) * 2;
  float s0 = 0.f, s1 = 0.f;
#pragma unroll 8
  for (int ks = 0; ks < KS; ++ks) {
    u32 v = *(const u32*)(gpart + (((size_t)ks * NB + b) * 256 + c) * 256 + d0);
    s0 += bf2f((unsigned short)(v & 0xffff));
    s1 += bf2f((unsigned short)(v >> 16));
  }
  *(float2*)(G + ((size_t)b * 256 + c) * 256 + d0) = make_float2(s0, s1);
}

// ---- T12 = Wcat @ G, fused with norms: nqk[b][r] = dot(T12[b][r], Wcat[r]) -
__global__ __launch_bounds__(256) void k_sgT(const float* __restrict__ Wcat,
                                             const float* __restrict__ G,
                                             float* __restrict__ T12,
                                             float* __restrict__ nqk) {
  const int t = threadIdx.x;
  const int r0 = blockIdx.x * 8, b = blockIdx.y;
  const float* Gb = G + (size_t)b * 65536 + t;
  float acc[8] = {0, 0, 0, 0, 0, 0, 0, 0};
#pragma unroll 4
  for (int k = 0; k < 256; ++k) {
    float bv = Gb[(size_t)k * 256];
#pragma unroll
    for (int o = 0; o < 8; ++o) acc[o] += Wcat[(r0 + o) * 256 + k] * bv;
  }
#pragma unroll
  for (int o = 0; o < 8; ++o)
    T12[(size_t)b * 131072 + (size_t)(r0 + o) * 256 + t] = acc[o];
  __shared__ float red[8][4];
  const int w = t >> 6, l = t & 63;
#pragma unroll
  for (int o = 0; o < 8; ++o) {
    float s = acc[o] * Wcat[(r0 + o) * 256 + t];
#pragma unroll
    for (int off = 32; off; off >>= 1) s += __shfl_xor(s, off);
    if (l == 0) red[o][w] = s;
  }
  __syncthreads();
  if (t < 8)
    nqk[b * 512 + r0 + t] = red[t][0] + red[t][1] + red[t][2] + red[t][3];
}

// ---- S = T1 @ Wk2^T fused with scaling + row-softmax -> attn ---------------
__global__ __launch_bounds__(256) void k_ssoft(const float* __restrict__ T12,
                                               const float* __restrict__ WkT,
                                               const float* __restrict__ nqk,
                                               const float* __restrict__ temp,
                                               float* __restrict__ attn) {
  const int t = threadIdx.x;
  const int c0 = blockIdx.x * 8, b = blockIdx.y;
  const float* Ab = T12 + (size_t)b * 131072 + (size_t)c0 * 256;  // T1 rows
  const float* Bb = WkT + t;
  float acc[8] = {0, 0, 0, 0, 0, 0, 0, 0};
#pragma unroll 4
  for (int k = 0; k < 256; ++k) {
    float bv = Bb[(size_t)k * 256];
#pragma unroll
    for (int o = 0; o < 8; ++o) acc[o] += Ab[o * 256 + k] * bv;
  }
  const float rk = 1.0f / fmaxf(sqrtf(fmaxf(nqk[b * 512 + 256 + t], 0.f)), 1e-12f);
  const float tau = temp[0];
#pragma unroll
  for (int o = 0; o < 8; ++o) {
    float rq = 1.0f / fmaxf(sqrtf(fmaxf(nqk[b * 512 + c0 + o], 0.f)), 1e-12f);
    acc[o] = acc[o] * rq * rk * tau;
  }
  __shared__ float redm[8][4];
  __shared__ float reds[8][4];
  const int w = t >> 6, l = t & 63;
#pragma unroll
  for (int o = 0; o < 8; ++o) {
    float m = acc[o];
#pragma unroll
    for (int off = 32; off; off >>= 1) m = fmaxf(m, __shfl_xor(m, off));
    if (l == 0) redm[o][w] = m;
  }
  __syncthreads();
  float e[8];
#pragma unroll
  for (int o = 0; o < 8; ++o) {
    float m = fmaxf(fmaxf(redm[o][0], redm[o][1]), fmaxf(redm[o][2], redm[o][3]));
    e[o] = __expf(acc[o] - m);
    float s = e[o];
#pragma unroll
    for (int off = 32; off; off >>= 1) s += __shfl_xor(s, off);
    if (l == 0) reds[o][w] = s;
  }
  __syncthreads();
#pragma unroll
  for (int o = 0; o < 8; ++o) {
    float tot = reds[o][0] + reds[o][1] + reds[o][2] + reds[o][3];
    attn[(size_t)b * 65536 + (size_t)(c0 + o) * 256 + t] = e[o] / tot;
  }
}

// ---- fused F = (Wp @ attn) @ Wv2, bf16 out ---------------------------------
__global__ __launch_bounds__(256) void k_sg2x(const float* __restrict__ wp,
                                              const float* __restrict__ attn,
                                              const float* __restrict__ wv2,
                                              char* __restrict__ Fb) {
  __shared__ float P[8 * 256];
  const int t = threadIdx.x;
  const int o0 = blockIdx.x * 8, b = blockIdx.y;
  const float* Ab = wp + (size_t)o0 * 256;
  const float* Bb = attn + (size_t)b * 65536 + t;
  float acc[8] = {0, 0, 0, 0, 0, 0, 0, 0};
#pragma unroll 4
  for (int k = 0; k < 256; ++k) {
    float bv = Bb[(size_t)k * 256];
#pragma unroll
    for (int o = 0; o < 8; ++o) acc[o] += Ab[o * 256 + k] * bv;
  }
#pragma unroll
  for (int o = 0; o < 8; ++o) P[o * 256 + t] = acc[o];
  __syncthreads();
  float a2[8] = {0, 0, 0, 0, 0, 0, 0, 0};
  const float* Bv = wv2 + t;
#pragma unroll 4
  for (int k = 0; k < 256; ++k) {
    float bv = Bv[(size_t)k * 256];
#pragma unroll
    for (int o = 0; o < 8; ++o) a2[o] += P[o * 256 + k] * bv;
  }
  unsigned short* Cp = (unsigned short*)Fb + (size_t)b * 65536;
#pragma unroll
  for (int o = 0; o < 8; ++o) Cp[(size_t)(o0 + o) * 256 + t] = f2bf(a2[o]);
}

// ---- final v2: out = F @ x via outT tiles; DIRECT fragment stores ----------
// C/D layout: acc[m][nq][r] -> o = ot*128+wn*64+nq*16+(l&15) (B-row),
// n = nt*128+wm*64+m*16+(l>>4)*4+r (A-row) — r is CONSECUTIVE in n, so each
// fragment stores one float4 straight to out[b][o][n..n+3] (64B-coalesced
// segments). Epilogue LDS bounce deleted; single 32KB buffer -> 4 blocks/CU.
__global__ __launch_bounds__(256) void k_final(const char* __restrict__ xt,
                                               const char* __restrict__ fb,
                                               float* __restrict__ out) {
  __shared__ char smem[32768];
  const int tid = threadIdx.x;
  const int nt = blockIdx.x, ot = blockIdx.y, b = blockIdx.z;
  const int w = tid >> 6, l = tid & 63;
  const int wm = w >> 1, wn = w & 1;
  f32x4 acc[4][4];
#pragma unroll
  for (int m = 0; m < 4; ++m)
#pragma unroll
    for (int nq = 0; nq < 4; ++nq) acc[m][nq] = (f32x4){0.f, 0.f, 0.f, 0.f};
  const char* Ap = xt + ((size_t)b * NN + (size_t)nt * 128) * 512;
  const char* Bp = fb + ((size_t)(b * 256 + ot * 128)) * 512;

  for (int kt = 0; kt < 4; ++kt) {
    stage_tile(Ap + kt * 128, 512, smem, w, l);
    stage_tile(Bp + kt * 128, 512, smem + 16384, w, l);
    __syncthreads();
#pragma unroll
    for (int ks = 0; ks < 2; ++ks) {
      bf16x8 av[4], bv[4];
      const int kb = ks * 64 + ((l >> 4) << 4);
#pragma unroll
      for (int m = 0; m < 4; ++m) {
        int row = wm * 64 + m * 16 + (l & 15);
        av[m] = *(const bf16x8*)(smem + row * 128 + (kb ^ ((row & 7) << 4)));
      }
#pragma unroll
      for (int nq = 0; nq < 4; ++nq) {
        int row = wn * 64 + nq * 16 + (l & 15);
        bv[nq] = *(const bf16x8*)(smem + 16384 + row * 128 +
                                  (kb ^ ((row & 7) << 4)));
      }
#pragma unroll
      for (int m = 0; m < 4; ++m)
#pragma unroll
        for (int nq = 0; nq < 4; ++nq)
          acc[m][nq] = __builtin_amdgcn_mfma_f32_16x16x32_bf16(
              av[m], bv[nq], acc[m][nq], 0, 0, 0);
    }
    __syncthreads();
  }
  // direct fragment stores: one float4 per fragment
#pragma unroll
  for (int m = 0; m < 4; ++m)
#pragma unroll
    for (int nq = 0; nq < 4; ++nq) {
      int o = ot * 128 + wn * 64 + nq * 16 + (l & 15);
      int n = nt * 128 + wm * 64 + m * 16 + ((l >> 4) << 2);
      *(f32x4*)(out + ((size_t)(b * 256 + o)) * NN + n) = acc[m][nq];
    }
}

extern "C" void kernel_launch(void* const* d_in, const int* in_sizes, int n_in,
                              void* d_out, int out_size, void* d_ws, size_t ws_size,
                              hipStream_t stream) {
  const float* x     = (const float*)d_in[0];
  const float* wqkv  = (const float*)d_in[1];
  const float* wdwf  = (const float*)d_in[2];
  const float* temp  = (const float*)d_in[3];
  const float* wproj = (const float*)d_in[4];
  float* out = (float*)d_out;
  char* ws = (char*)d_ws;

  // Workspace layout (bytes); total ~145 MB
  char*  xt    = ws;                            // bf16 [B][N][C]      67,108,864
  unsigned short* gpart = (unsigned short*)(ws + 67108864);
                                                // bf16 [64][B][256][256] 67,108,864
  float* G     = (float*)(ws + 134217728);      // f32 [B][256][256]    2,097,152
  float* T12   = (float*)(ws + 136314880);      // f32 [B][512][256]    4,194,304
  float* attn  = (float*)(ws + 140509184);      // f32 [B][256][256]    2,097,152
  char*  Fb    = ws + 142606336;                // bf16 [B][256][256]   1,048,576
  float* Wcat  = (float*)(ws + 143654912);      // f32 [512][256]         524,288
  float* WkT   = (float*)(ws + 144179200);      // f32 [256][256]         262,144
  float* Wv2   = (float*)(ws + 144441344);      // f32 [256][256]         262,144
  float* nqk   = (float*)(ws + 144703488);      // f32 [B][512]            16,384

  // fused gram + transpose-convert + weight-prep (576 blocks x 1024 thr)
  k_gramT<<<dim3(KS * NB + 64), dim3(1024), 0, stream>>>(
      x, gpart, xt, wqkv, wdwf, Wcat, WkT, Wv2);
  k_reduceG<<<dim3(128, NB), dim3(256), 0, stream>>>(gpart, G);
  k_sgT<<<dim3(64, NB), dim3(256), 0, stream>>>(Wcat, G, T12, nqk);
  k_ssoft<<<dim3(32, NB), dim3(256), 0, stream>>>(T12, WkT, nqk, temp, attn);
  k_sg2x<<<dim3(32, NB), dim3(256), 0, stream>>>(wproj, attn, Wv2, Fb);
  k_final<<<dim3(128, 2, NB), dim3(256), 0, stream>>>(xt, Fb, out);
}

// Round 19
// 203.868 us; speedup vs baseline: 1.1459x; 1.1459x over previous
//
#include <hip/hip_runtime.h>
#include <hip/hip_bf16.h>
#include <stdint.h>

// Problem constants
#define NB 8
#define NC 256
#define NN 16384
#define KS 32        // gram k-split: 32 chunks of 512 (8 ktiles of 64)

typedef short bf16x8 __attribute__((ext_vector_type(8)));  // 8 bf16 = 4 VGPR
typedef float f32x4  __attribute__((ext_vector_type(4)));
typedef uint32_t u32;

__device__ __forceinline__ unsigned short f2bf(float f) {
  union { float f; unsigned u; } c; c.f = f;
  return (unsigned short)((c.u + 0x7FFFu + ((c.u >> 16) & 1u)) >> 16);  // RNE
}
__device__ __forceinline__ float bf2f(unsigned short h) {
  union { unsigned u; float f; } c; c.u = ((unsigned)h) << 16;
  return c.f;
}
// pack float2 -> 2 bf16 in a u32 (RNE, same rounding as f2bf)
__device__ __forceinline__ u32 pk2(float a, float b) {
  union { __hip_bfloat162 h; u32 u; } c;
  c.h = __float22bfloat162_rn(make_float2(a, b));
  return c.u;
}

// async global->LDS, 16B per lane; LDS dest is wave-uniform base + lane*16
__device__ __forceinline__ void gload16(const void* g, void* l) {
  __builtin_amdgcn_global_load_lds(
      (const __attribute__((address_space(1))) u32*)g,
      (__attribute__((address_space(3))) u32*)l, 16, 0, 0);
}

// Stage a [128 rows x 64 bf16] tile (row stride ld_bytes) into 16KB of LDS.
// T2 XOR-swizzle applied on the per-lane global source; LDS stays linear.
__device__ __forceinline__ void stage_tile(const char* src, int ld_bytes,
                                           char* lds, int w, int l) {
#pragma unroll
  for (int i = 0; i < 4; ++i) {
    int s = (w * 4 + i) * 64 + l;      // 0..1023 : 16B chunk index
    int row = s >> 3;
    int srcslot = (l & 7) ^ (row & 7);
    gload16(src + (size_t)row * ld_bytes + srcslot * 16,
            lds + (w * 4 + i) * 1024);
  }
}

// ---- gramT v6: pure reg-staged bf16 gram (NO xt) + prepw ------------------
// blocks [0,256): gram, one (ks,b) each; K-chunk 512 = 8 ktiles of 64.
// blocks [256,320): weight prep (4 rows per block).
__global__ __launch_bounds__(1024) void k_gramT(
    const float* __restrict__ x, unsigned short* __restrict__ gpart,
    const float* __restrict__ wqkv, const float* __restrict__ wdw,
    float* __restrict__ Wcat, float* __restrict__ WkT,
    float* __restrict__ Wv2) {
  __shared__ __align__(16) unsigned short tile[256 * 72];  // 36 KB
  const int bid = blockIdx.x;
  const int tid = threadIdx.x;

  if (bid >= KS * NB) {
    // ---------------- prepw role ----------------
    const int r = (bid - KS * NB) * 4 + (tid >> 8);
    const int t = tid & 255;
    Wcat[r * 256 + t] = wqkv[r * 256 + t] * wdw[r];
    float kv = wqkv[(256 + r) * 256 + t] * wdw[256 + r];
    Wcat[65536 + r * 256 + t] = kv;
    WkT[t * 256 + r] = kv;
    Wv2[r * 256 + t] = wqkv[(512 + r) * 256 + t] * wdw[512 + r];
    return;
  }

  // ---------------- gram role ----------------
  const int ks = bid & (KS - 1), b = bid >> 5;
  const int w = tid >> 6, l = tid & 63;
  const int wm = w >> 2, wn = w & 3;           // 4m x 4n wave grid
  const int c0 = (tid >> 4) * 4, n0 = (tid & 15) * 4;   // staging coords
  f32x4 acc[4][4];
#pragma unroll
  for (int m = 0; m < 4; ++m)
#pragma unroll
    for (int n = 0; n < 4; ++n) acc[m][n] = (f32x4){0.f, 0.f, 0.f, 0.f};
  const float* x0 = x + (size_t)b * NC * NN + (size_t)ks * 512;

  float4 f[4];     // fp32 staging (one generation)
  u32 hw[4][2];    // bf16 staging: hw[j] = 4 bf16 of row c0+j, cols n0..n0+3

#define LOADS(kt)                                                           \
  {                                                                         \
    _Pragma("unroll") for (int j = 0; j < 4; ++j)                           \
        f[j] = *(const float4*)&x0[(size_t)(c0 + j) * NN + (kt) * 64 + n0]; \
  }
#define CVT()                                                               \
  {                                                                         \
    _Pragma("unroll") for (int j = 0; j < 4; ++j) {                         \
      hw[j][0] = pk2(f[j].x, f[j].y);                                       \
      hw[j][1] = pk2(f[j].z, f[j].w);                                       \
    }                                                                       \
  }
#define DSW()                                                               \
  {                                                                         \
    _Pragma("unroll") for (int j = 0; j < 4; ++j)                           \
        *(uint2*)&tile[(c0 + j) * 72 + n0] = make_uint2(hw[j][0], hw[j][1]);\
  }

  // prologue: tile 0
  LOADS(0); CVT(); DSW();
  __syncthreads();

  for (int kt = 0; kt < 8; ++kt) {
    if (kt < 7) LOADS(kt + 1);   // issue next loads; land in regs during MFMA
    // ---- MFMA from bf16 tile (one b128 read per fragment) ----
#pragma unroll
    for (int ks2 = 0; ks2 < 2; ++ks2) {
      const int ko = ks2 * 32 + (l >> 4) * 8;   // elem offset of lane's 8 bf16
      bf16x8 av[4], bv[4];
#pragma unroll
      for (int m = 0; m < 4; ++m) {
        int row = wm * 64 + m * 16 + (l & 15);
        av[m] = *(const bf16x8*)&tile[row * 72 + ko];
      }
#pragma unroll
      for (int n = 0; n < 4; ++n) {
        int row = wn * 64 + n * 16 + (l & 15);
        bv[n] = *(const bf16x8*)&tile[row * 72 + ko];
      }
#pragma unroll
      for (int m = 0; m < 4; ++m)
#pragma unroll
        for (int n = 0; n < 4; ++n)
          acc[m][n] = __builtin_amdgcn_mfma_f32_16x16x32_bf16(
              av[m], bv[n], acc[m][n], 0, 0, 0);
    }
    __syncthreads();             // tile consumed; safe to overwrite
    if (kt < 7) {
      CVT();                     // vmcnt for LOADS(kt+1) waits here (hidden)
      DSW();
      __syncthreads();           // tile(kt+1) ready
    }
  }
#undef LOADS
#undef CVT
#undef DSW
  // ---- gpart epilogue (bf16) ----
  unsigned short* gp = gpart + ((size_t)(ks * NB + b)) * 65536;
#pragma unroll
  for (int m = 0; m < 4; ++m)
#pragma unroll
    for (int n = 0; n < 4; ++n)
#pragma unroll
      for (int r = 0; r < 4; ++r) {
        int c = wm * 64 + m * 16 + ((l >> 4) << 2) + r;
        int d = wn * 64 + n * 16 + (l & 15);
        gp[(size_t)c * 256 + d] = f2bf(acc[m][n][r]);
      }
}

// ---- G[b] = sum_ks gpart (bf16 in, fp32 out); grid (128, NB) ---------------
__global__ __launch_bounds__(256) void k_reduceG(
    const unsigned short* __restrict__ gpart, float* __restrict__ G) {
  const int t = threadIdx.x;
  const int c = blockIdx.x * 2 + (t >> 7), b = blockIdx.y;
  const int d0 = (t & 127) * 2;
  float s0 = 0.f, s1 = 0.f;
#pragma unroll 8
  for (int ks = 0; ks < KS; ++ks) {
    u32 v = *(const u32*)(gpart + (((size_t)ks * NB + b) * 256 + c) * 256 + d0);
    s0 += bf2f((unsigned short)(v & 0xffff));
    s1 += bf2f((unsigned short)(v >> 16));
  }
  *(float2*)(G + ((size_t)b * 256 + c) * 256 + d0) = make_float2(s0, s1);
}

// ---- T12 = Wcat @ G, fused with norms: nqk[b][r] = dot(T12[b][r], Wcat[r]) -
__global__ __launch_bounds__(256) void k_sgT(const float* __restrict__ Wcat,
                                             const float* __restrict__ G,
                                             float* __restrict__ T12,
                                             float* __restrict__ nqk) {
  const int t = threadIdx.x;
  const int r0 = blockIdx.x * 8, b = blockIdx.y;
  const float* Gb = G + (size_t)b * 65536 + t;
  float acc[8] = {0, 0, 0, 0, 0, 0, 0, 0};
#pragma unroll 4
  for (int k = 0; k < 256; ++k) {
    float bv = Gb[(size_t)k * 256];
#pragma unroll
    for (int o = 0; o < 8; ++o) acc[o] += Wcat[(r0 + o) * 256 + k] * bv;
  }
#pragma unroll
  for (int o = 0; o < 8; ++o)
    T12[(size_t)b * 131072 + (size_t)(r0 + o) * 256 + t] = acc[o];
  __shared__ float red[8][4];
  const int w = t >> 6, l = t & 63;
#pragma unroll
  for (int o = 0; o < 8; ++o) {
    float s = acc[o] * Wcat[(r0 + o) * 256 + t];
#pragma unroll
    for (int off = 32; off; off >>= 1) s += __shfl_xor(s, off);
    if (l == 0) red[o][w] = s;
  }
  __syncthreads();
  if (t < 8)
    nqk[b * 512 + r0 + t] = red[t][0] + red[t][1] + red[t][2] + red[t][3];
}

// ---- S = T1 @ Wk2^T fused with scaling + row-softmax -> attn ---------------
__global__ __launch_bounds__(256) void k_ssoft(const float* __restrict__ T12,
                                               const float* __restrict__ WkT,
                                               const float* __restrict__ nqk,
                                               const float* __restrict__ temp,
                                               float* __restrict__ attn) {
  const int t = threadIdx.x;
  const int c0 = blockIdx.x * 8, b = blockIdx.y;
  const float* Ab = T12 + (size_t)b * 131072 + (size_t)c0 * 256;  // T1 rows
  const float* Bb = WkT + t;
  float acc[8] = {0, 0, 0, 0, 0, 0, 0, 0};
#pragma unroll 4
  for (int k = 0; k < 256; ++k) {
    float bv = Bb[(size_t)k * 256];
#pragma unroll
    for (int o = 0; o < 8; ++o) acc[o] += Ab[o * 256 + k] * bv;
  }
  const float rk = 1.0f / fmaxf(sqrtf(fmaxf(nqk[b * 512 + 256 + t], 0.f)), 1e-12f);
  const float tau = temp[0];
#pragma unroll
  for (int o = 0; o < 8; ++o) {
    float rq = 1.0f / fmaxf(sqrtf(fmaxf(nqk[b * 512 + c0 + o], 0.f)), 1e-12f);
    acc[o] = acc[o] * rq * rk * tau;
  }
  __shared__ float redm[8][4];
  __shared__ float reds[8][4];
  const int w = t >> 6, l = t & 63;
#pragma unroll
  for (int o = 0; o < 8; ++o) {
    float m = acc[o];
#pragma unroll
    for (int off = 32; off; off >>= 1) m = fmaxf(m, __shfl_xor(m, off));
    if (l == 0) redm[o][w] = m;
  }
  __syncthreads();
  float e[8];
#pragma unroll
  for (int o = 0; o < 8; ++o) {
    float m = fmaxf(fmaxf(redm[o][0], redm[o][1]), fmaxf(redm[o][2], redm[o][3]));
    e[o] = __expf(acc[o] - m);
    float s = e[o];
#pragma unroll
    for (int off = 32; off; off >>= 1) s += __shfl_xor(s, off);
    if (l == 0) reds[o][w] = s;
  }
  __syncthreads();
#pragma unroll
  for (int o = 0; o < 8; ++o) {
    float tot = reds[o][0] + reds[o][1] + reds[o][2] + reds[o][3];
    attn[(size_t)b * 65536 + (size_t)(c0 + o) * 256 + t] = e[o] / tot;
  }
}

// ---- fused F = (Wp @ attn) @ Wv2, bf16 out ---------------------------------
__global__ __launch_bounds__(256) void k_sg2x(const float* __restrict__ wp,
                                              const float* __restrict__ attn,
                                              const float* __restrict__ wv2,
                                              char* __restrict__ Fb) {
  __shared__ float P[8 * 256];
  const int t = threadIdx.x;
  const int o0 = blockIdx.x * 8, b = blockIdx.y;
  const float* Ab = wp + (size_t)o0 * 256;
  const float* Bb = attn + (size_t)b * 65536 + t;
  float acc[8] = {0, 0, 0, 0, 0, 0, 0, 0};
#pragma unroll 4
  for (int k = 0; k < 256; ++k) {
    float bv = Bb[(size_t)k * 256];
#pragma unroll
    for (int o = 0; o < 8; ++o) acc[o] += Ab[o * 256 + k] * bv;
  }
#pragma unroll
  for (int o = 0; o < 8; ++o) P[o * 256 + t] = acc[o];
  __syncthreads();
  float a2[8] = {0, 0, 0, 0, 0, 0, 0, 0};
  const float* Bv = wv2 + t;
#pragma unroll 4
  for (int k = 0; k < 256; ++k) {
    float bv = Bv[(size_t)k * 256];
#pragma unroll
    for (int o = 0; o < 8; ++o) a2[o] += P[o * 256 + k] * bv;
  }
  unsigned short* Cp = (unsigned short*)Fb + (size_t)b * 65536;
#pragma unroll
  for (int o = 0; o < 8; ++o) Cp[(size_t)(o0 + o) * 256 + t] = f2bf(a2[o]);
}

// ---- final v3: out = F @ x; A staged FROM x with in-reg transpose-convert --
// A-frag = xt[n][c..c+7] = x[c..c+7][n]: load x [c][n] float4s (coalesced
// along n), cvt once (pk2), store transposed into At[128 n][72 c] (pad-72
// rows). B (Fb) and direct-fragment-store epilogue verbatim from r18. xt is
// GONE from the pipeline.
__global__ __launch_bounds__(256) void k_final(const float* __restrict__ x,
                                               const char* __restrict__ fb,
                                               float* __restrict__ out) {
  __shared__ __align__(16) unsigned short At[128 * 72];  // 18 KB
  __shared__ __align__(16) char Bs[16384];
  const int tid = threadIdx.x;
  const int nt = blockIdx.x, ot = blockIdx.y, b = blockIdx.z;
  const int w = tid >> 6, l = tid & 63;
  const int wm = w >> 1, wn = w & 1;
  const int c0 = (tid & 7) * 8, n0 = (tid >> 3) * 4;   // A-staging coords
  f32x4 acc[4][4];
#pragma unroll
  for (int m = 0; m < 4; ++m)
#pragma unroll
    for (int nq = 0; nq < 4; ++nq) acc[m][nq] = (f32x4){0.f, 0.f, 0.f, 0.f};
  const float* xb = x + (size_t)b * NC * NN + (size_t)nt * 128;
  const char* Bp = fb + ((size_t)(b * 256 + ot * 128)) * 512;

  for (int kt = 0; kt < 4; ++kt) {
    // B stage (async global->LDS)
    stage_tile(Bp + kt * 128, 512, Bs, w, l);
    // A stage: x[kt*64 + c0+g*4+j][n0..n0+3] -> At[n0+k][c0+g*4 ..]
#pragma unroll
    for (int g = 0; g < 2; ++g) {
      float4 f[4];
#pragma unroll
      for (int j = 0; j < 4; ++j)
        f[j] = *(const float4*)&xb[(size_t)(kt * 64 + c0 + g * 4 + j) * NN + n0];
#pragma unroll
      for (int k = 0; k < 4; ++k) {
        float v0 = ((const float*)&f[0])[k], v1 = ((const float*)&f[1])[k];
        float v2 = ((const float*)&f[2])[k], v3 = ((const float*)&f[3])[k];
        *(uint2*)&At[(n0 + k) * 72 + c0 + g * 4] =
            make_uint2(pk2(v0, v1), pk2(v2, v3));
      }
    }
    __syncthreads();
#pragma unroll
    for (int ks = 0; ks < 2; ++ks) {
      const int kb = ks * 64 + ((l >> 4) << 4);   // byte off in Bs rows
      const int ko = ks * 32 + ((l >> 4) << 3);   // elem off in At rows
      bf16x8 av[4], bv[4];
#pragma unroll
      for (int m = 0; m < 4; ++m) {
        int row = wm * 64 + m * 16 + (l & 15);
        av[m] = *(const bf16x8*)&At[row * 72 + ko];
      }
#pragma unroll
      for (int nq = 0; nq < 4; ++nq) {
        int row = wn * 64 + nq * 16 + (l & 15);
        bv[nq] = *(const bf16x8*)(Bs + row * 128 + (kb ^ ((row & 7) << 4)));
      }
#pragma unroll
      for (int m = 0; m < 4; ++m)
#pragma unroll
        for (int nq = 0; nq < 4; ++nq)
          acc[m][nq] = __builtin_amdgcn_mfma_f32_16x16x32_bf16(
              av[m], bv[nq], acc[m][nq], 0, 0, 0);
    }
    __syncthreads();
  }
  // direct fragment stores: one float4 per fragment (r18, verified)
#pragma unroll
  for (int m = 0; m < 4; ++m)
#pragma unroll
    for (int nq = 0; nq < 4; ++nq) {
      int o = ot * 128 + wn * 64 + nq * 16 + (l & 15);
      int n = nt * 128 + wm * 64 + m * 16 + ((l >> 4) << 2);
      *(f32x4*)(out + ((size_t)(b * 256 + o)) * NN + n) = acc[m][nq];
    }
}

extern "C" void kernel_launch(void* const* d_in, const int* in_sizes, int n_in,
                              void* d_out, int out_size, void* d_ws, size_t ws_size,
                              hipStream_t stream) {
  const float* x     = (const float*)d_in[0];
  const float* wqkv  = (const float*)d_in[1];
  const float* wdwf  = (const float*)d_in[2];
  const float* temp  = (const float*)d_in[3];
  const float* wproj = (const float*)d_in[4];
  float* out = (float*)d_out;
  char* ws = (char*)d_ws;

  // Workspace layout (bytes); total ~45 MB (xt deleted)
  unsigned short* gpart = (unsigned short*)ws;  // bf16 [32][B][256][256] 33,554,432
  float* G     = (float*)(ws + 33554432);       // f32 [B][256][256]    2,097,152
  float* T12   = (float*)(ws + 35651584);       // f32 [B][512][256]    4,194,304
  float* attn  = (float*)(ws + 39845888);       // f32 [B][256][256]    2,097,152
  char*  Fb    = ws + 41943040;                 // bf16 [B][256][256]   1,048,576
  float* Wcat  = (float*)(ws + 42991616);       // f32 [512][256]         524,288
  float* WkT   = (float*)(ws + 43515904);       // f32 [256][256]         262,144
  float* Wv2   = (float*)(ws + 43778048);       // f32 [256][256]         262,144
  float* nqk   = (float*)(ws + 44040192);       // f32 [B][512]            16,384

  // fused gram + weight-prep (320 blocks x 1024 threads)
  k_gramT<<<dim3(KS * NB + 64), dim3(1024), 0, stream>>>(
      x, gpart, wqkv, wdwf, Wcat, WkT, Wv2);
  k_reduceG<<<dim3(128, NB), dim3(256), 0, stream>>>(gpart, G);
  k_sgT<<<dim3(64, NB), dim3(256), 0, stream>>>(Wcat, G, T12, nqk);
  k_ssoft<<<dim3(32, NB), dim3(256), 0, stream>>>(T12, WkT, nqk, temp, attn);
  k_sg2x<<<dim3(32, NB), dim3(256), 0, stream>>>(wproj, attn, Wv2, Fb);
  k_final<<<dim3(128, 2, NB), dim3(256), 0, stream>>>(x, Fb, out);
}

// Round 20
// 202.880 us; speedup vs baseline: 1.1515x; 1.0049x over previous
//
#include <hip/hip_runtime.h>
#include <hip/hip_bf16.h>
#include <stdint.h>

// Problem constants
#define NB 8
#define NC 256
#define NN 16384
#define KS 32        // gram k-split: 32 chunks of 512 (8 ktiles of 64)

typedef short bf16x8 __attribute__((ext_vector_type(8)));  // 8 bf16 = 4 VGPR
typedef float f32x4  __attribute__((ext_vector_type(4)));
typedef uint32_t u32;

__device__ __forceinline__ unsigned short f2bf(float f) {
  union { float f; unsigned u; } c; c.f = f;
  return (unsigned short)((c.u + 0x7FFFu + ((c.u >> 16) & 1u)) >> 16);  // RNE
}
__device__ __forceinline__ float bf2f(unsigned short h) {
  union { unsigned u; float f; } c; c.u = ((unsigned)h) << 16;
  return c.f;
}
// pack float2 -> 2 bf16 in a u32 (RNE, same rounding as f2bf)
__device__ __forceinline__ u32 pk2(float a, float b) {
  union { __hip_bfloat162 h; u32 u; } c;
  c.h = __float22bfloat162_rn(make_float2(a, b));
  return c.u;
}

// async global->LDS, 16B per lane; LDS dest is wave-uniform base + lane*16
__device__ __forceinline__ void gload16(const void* g, void* l) {
  __builtin_amdgcn_global_load_lds(
      (const __attribute__((address_space(1))) u32*)g,
      (__attribute__((address_space(3))) u32*)l, 16, 0, 0);
}

// Stage a [128 rows x 64 bf16] tile (row stride ld_bytes) into 16KB of LDS.
// T2 XOR-swizzle applied on the per-lane global source; LDS stays linear.
__device__ __forceinline__ void stage_tile(const char* src, int ld_bytes,
                                           char* lds, int w, int l) {
#pragma unroll
  for (int i = 0; i < 4; ++i) {
    int s = (w * 4 + i) * 64 + l;      // 0..1023 : 16B chunk index
    int row = s >> 3;
    int srcslot = (l & 7) ^ (row & 7);
    gload16(src + (size_t)row * ld_bytes + srcslot * 16,
            lds + (w * 4 + i) * 1024);
  }
}

// ---- gramT v7: reg-staged bf16 gram, DBUF tile -> ONE barrier per ktile ----
// blocks [0,256): gram, one (ks,b) each; K-chunk 512 = 8 ktiles of 64.
// blocks [256,320): weight prep (4 rows per block).
// Per ktile: LOADS(kt+1) -> MFMA(tile[cur]) -> CVT+DSW(tile[cur^1]) -> sync.
// Buffers disjoint => no write-read hazard; 8 barriers/block (was 16).
__global__ __launch_bounds__(1024) void k_gramT(
    const float* __restrict__ x, unsigned short* __restrict__ gpart,
    const float* __restrict__ wqkv, const float* __restrict__ wdw,
    float* __restrict__ Wcat, float* __restrict__ WkT,
    float* __restrict__ Wv2) {
  __shared__ __align__(16) unsigned short tile[2][256 * 72];  // 2 x 36 KB
  const int bid = blockIdx.x;
  const int tid = threadIdx.x;

  if (bid >= KS * NB) {
    // ---------------- prepw role ----------------
    const int r = (bid - KS * NB) * 4 + (tid >> 8);
    const int t = tid & 255;
    Wcat[r * 256 + t] = wqkv[r * 256 + t] * wdw[r];
    float kv = wqkv[(256 + r) * 256 + t] * wdw[256 + r];
    Wcat[65536 + r * 256 + t] = kv;
    WkT[t * 256 + r] = kv;
    Wv2[r * 256 + t] = wqkv[(512 + r) * 256 + t] * wdw[512 + r];
    return;
  }

  // ---------------- gram role ----------------
  const int ks = bid & (KS - 1), b = bid >> 5;
  const int w = tid >> 6, l = tid & 63;
  const int wm = w >> 2, wn = w & 3;           // 4m x 4n wave grid
  const int c0 = (tid >> 4) * 4, n0 = (tid & 15) * 4;   // staging coords
  f32x4 acc[4][4];
#pragma unroll
  for (int m = 0; m < 4; ++m)
#pragma unroll
    for (int n = 0; n < 4; ++n) acc[m][n] = (f32x4){0.f, 0.f, 0.f, 0.f};
  const float* x0 = x + (size_t)b * NC * NN + (size_t)ks * 512;

  float4 f[4];     // fp32 staging (one generation)
  u32 hw[4][2];    // bf16 staging: hw[j] = 4 bf16 of row c0+j, cols n0..n0+3

#define LOADS(kt)                                                           \
  {                                                                         \
    _Pragma("unroll") for (int j = 0; j < 4; ++j)                           \
        f[j] = *(const float4*)&x0[(size_t)(c0 + j) * NN + (kt) * 64 + n0]; \
  }
#define CVT()                                                               \
  {                                                                         \
    _Pragma("unroll") for (int j = 0; j < 4; ++j) {                         \
      hw[j][0] = pk2(f[j].x, f[j].y);                                       \
      hw[j][1] = pk2(f[j].z, f[j].w);                                       \
    }                                                                       \
  }
#define DSW(buf)                                                            \
  {                                                                         \
    _Pragma("unroll") for (int j = 0; j < 4; ++j)                           \
        *(uint2*)&tile[buf][(c0 + j) * 72 + n0] =                           \
            make_uint2(hw[j][0], hw[j][1]);                                 \
  }

  // prologue: tile 0 into buf 0
  LOADS(0); CVT(); DSW(0);
  __syncthreads();

  for (int kt = 0; kt < 8; ++kt) {
    const int cur = kt & 1;
    if (kt < 7) LOADS(kt + 1);   // issue next loads; fly during MFMA
    // ---- MFMA from tile[cur] (one b128 read per fragment) ----
#pragma unroll
    for (int ks2 = 0; ks2 < 2; ++ks2) {
      const int ko = ks2 * 32 + (l >> 4) * 8;   // elem offset of lane's 8 bf16
      bf16x8 av[4], bv[4];
#pragma unroll
      for (int m = 0; m < 4; ++m) {
        int row = wm * 64 + m * 16 + (l & 15);
        av[m] = *(const bf16x8*)&tile[cur][row * 72 + ko];
      }
#pragma unroll
      for (int n = 0; n < 4; ++n) {
        int row = wn * 64 + n * 16 + (l & 15);
        bv[n] = *(const bf16x8*)&tile[cur][row * 72 + ko];
      }
#pragma unroll
      for (int m = 0; m < 4; ++m)
#pragma unroll
        for (int n = 0; n < 4; ++n)
          acc[m][n] = __builtin_amdgcn_mfma_f32_16x16x32_bf16(
              av[m], bv[n], acc[m][n], 0, 0, 0);
    }
    if (kt < 7) {
      CVT();                     // waits vmcnt for LOADS(kt+1) (hidden by MFMA)
      DSW(cur ^ 1);              // write OTHER buffer: no hazard with readers
      __syncthreads();           // publish tile[cur^1] for next MFMA
    }
  }
#undef LOADS
#undef CVT
#undef DSW
  // ---- gpart epilogue (bf16) ----
  unsigned short* gp = gpart + ((size_t)(ks * NB + b)) * 65536;
#pragma unroll
  for (int m = 0; m < 4; ++m)
#pragma unroll
    for (int n = 0; n < 4; ++n)
#pragma unroll
      for (int r = 0; r < 4; ++r) {
        int c = wm * 64 + m * 16 + ((l >> 4) << 2) + r;
        int d = wn * 64 + n * 16 + (l & 15);
        gp[(size_t)c * 256 + d] = f2bf(acc[m][n][r]);
      }
}

// ---- G[b] = sum_ks gpart (bf16 in, fp32 out); grid (128, NB) ---------------
__global__ __launch_bounds__(256) void k_reduceG(
    const unsigned short* __restrict__ gpart, float* __restrict__ G) {
  const int t = threadIdx.x;
  const int c = blockIdx.x * 2 + (t >> 7), b = blockIdx.y;
  const int d0 = (t & 127) * 2;
  float s0 = 0.f, s1 = 0.f;
#pragma unroll 8
  for (int ks = 0; ks < KS; ++ks) {
    u32 v = *(const u32*)(gpart + (((size_t)ks * NB + b) * 256 + c) * 256 + d0);
    s0 += bf2f((unsigned short)(v & 0xffff));
    s1 += bf2f((unsigned short)(v >> 16));
  }
  *(float2*)(G + ((size_t)b * 256 + c) * 256 + d0) = make_float2(s0, s1);
}

// ---- T12 = Wcat @ G, fused with norms: nqk[b][r] = dot(T12[b][r], Wcat[r]) -
__global__ __launch_bounds__(256) void k_sgT(const float* __restrict__ Wcat,
                                             const float* __restrict__ G,
                                             float* __restrict__ T12,
                                             float* __restrict__ nqk) {
  const int t = threadIdx.x;
  const int r0 = blockIdx.x * 8, b = blockIdx.y;
  const float* Gb = G + (size_t)b * 65536 + t;
  float acc[8] = {0, 0, 0, 0, 0, 0, 0, 0};
#pragma unroll 4
  for (int k = 0; k < 256; ++k) {
    float bv = Gb[(size_t)k * 256];
#pragma unroll
    for (int o = 0; o < 8; ++o) acc[o] += Wcat[(r0 + o) * 256 + k] * bv;
  }
#pragma unroll
  for (int o = 0; o < 8; ++o)
    T12[(size_t)b * 131072 + (size_t)(r0 + o) * 256 + t] = acc[o];
  __shared__ float red[8][4];
  const int w = t >> 6, l = t & 63;
#pragma unroll
  for (int o = 0; o < 8; ++o) {
    float s = acc[o] * Wcat[(r0 + o) * 256 + t];
#pragma unroll
    for (int off = 32; off; off >>= 1) s += __shfl_xor(s, off);
    if (l == 0) red[o][w] = s;
  }
  __syncthreads();
  if (t < 8)
    nqk[b * 512 + r0 + t] = red[t][0] + red[t][1] + red[t][2] + red[t][3];
}

// ---- S = T1 @ Wk2^T fused with scaling + row-softmax -> attn ---------------
__global__ __launch_bounds__(256) void k_ssoft(const float* __restrict__ T12,
                                               const float* __restrict__ WkT,
                                               const float* __restrict__ nqk,
                                               const float* __restrict__ temp,
                                               float* __restrict__ attn) {
  const int t = threadIdx.x;
  const int c0 = blockIdx.x * 8, b = blockIdx.y;
  const float* Ab = T12 + (size_t)b * 131072 + (size_t)c0 * 256;  // T1 rows
  const float* Bb = WkT + t;
  float acc[8] = {0, 0, 0, 0, 0, 0, 0, 0};
#pragma unroll 4
  for (int k = 0; k < 256; ++k) {
    float bv = Bb[(size_t)k * 256];
#pragma unroll
    for (int o = 0; o < 8; ++o) acc[o] += Ab[o * 256 + k] * bv;
  }
  const float rk = 1.0f / fmaxf(sqrtf(fmaxf(nqk[b * 512 + 256 + t], 0.f)), 1e-12f);
  const float tau = temp[0];
#pragma unroll
  for (int o = 0; o < 8; ++o) {
    float rq = 1.0f / fmaxf(sqrtf(fmaxf(nqk[b * 512 + c0 + o], 0.f)), 1e-12f);
    acc[o] = acc[o] * rq * rk * tau;
  }
  __shared__ float redm[8][4];
  __shared__ float reds[8][4];
  const int w = t >> 6, l = t & 63;
#pragma unroll
  for (int o = 0; o < 8; ++o) {
    float m = acc[o];
#pragma unroll
    for (int off = 32; off; off >>= 1) m = fmaxf(m, __shfl_xor(m, off));
    if (l == 0) redm[o][w] = m;
  }
  __syncthreads();
  float e[8];
#pragma unroll
  for (int o = 0; o < 8; ++o) {
    float m = fmaxf(fmaxf(redm[o][0], redm[o][1]), fmaxf(redm[o][2], redm[o][3]));
    e[o] = __expf(acc[o] - m);
    float s = e[o];
#pragma unroll
    for (int off = 32; off; off >>= 1) s += __shfl_xor(s, off);
    if (l == 0) reds[o][w] = s;
  }
  __syncthreads();
#pragma unroll
  for (int o = 0; o < 8; ++o) {
    float tot = reds[o][0] + reds[o][1] + reds[o][2] + reds[o][3];
    attn[(size_t)b * 65536 + (size_t)(c0 + o) * 256 + t] = e[o] / tot;
  }
}

// ---- fused F = (Wp @ attn) @ Wv2, bf16 out ---------------------------------
__global__ __launch_bounds__(256) void k_sg2x(const float* __restrict__ wp,
                                              const float* __restrict__ attn,
                                              const float* __restrict__ wv2,
                                              char* __restrict__ Fb) {
  __shared__ float P[8 * 256];
  const int t = threadIdx.x;
  const int o0 = blockIdx.x * 8, b = blockIdx.y;
  const float* Ab = wp + (size_t)o0 * 256;
  const float* Bb = attn + (size_t)b * 65536 + t;
  float acc[8] = {0, 0, 0, 0, 0, 0, 0, 0};
#pragma unroll 4
  for (int k = 0; k < 256; ++k) {
    float bv = Bb[(size_t)k * 256];
#pragma unroll
    for (int o = 0; o < 8; ++o) acc[o] += Ab[o * 256 + k] * bv;
  }
#pragma unroll
  for (int o = 0; o < 8; ++o) P[o * 256 + t] = acc[o];
  __syncthreads();
  float a2[8] = {0, 0, 0, 0, 0, 0, 0, 0};
  const float* Bv = wv2 + t;
#pragma unroll 4
  for (int k = 0; k < 256; ++k) {
    float bv = Bv[(size_t)k * 256];
#pragma unroll
    for (int o = 0; o < 8; ++o) a2[o] += P[o * 256 + k] * bv;
  }
  unsigned short* Cp = (unsigned short*)Fb + (size_t)b * 65536;
#pragma unroll
  for (int o = 0; o < 8; ++o) Cp[(size_t)(o0 + o) * 256 + t] = f2bf(a2[o]);
}

// ---- final v4: out = F @ x; dbuf A+B staging, ONE barrier per ktile --------
// A staged from x with in-reg transpose-convert into At[cur^1] while MFMA
// reads At[cur]; B prefetched via async stage_tile into Bs[cur^1] (issued
// before MFMA, flies during compute). Direct-fragment-store epilogue (r18).
__global__ __launch_bounds__(256) void k_final(const float* __restrict__ x,
                                               const char* __restrict__ fb,
                                               float* __restrict__ out) {
  __shared__ __align__(16) unsigned short At[2][128 * 72];  // 2 x 18 KB
  __shared__ __align__(16) char Bs[2][16384];               // 2 x 16 KB
  const int tid = threadIdx.x;
  const int nt = blockIdx.x, ot = blockIdx.y, b = blockIdx.z;
  const int w = tid >> 6, l = tid & 63;
  const int wm = w >> 1, wn = w & 1;
  const int c0 = (tid & 7) * 8, n0 = (tid >> 3) * 4;   // A-staging coords
  f32x4 acc[4][4];
#pragma unroll
  for (int m = 0; m < 4; ++m)
#pragma unroll
    for (int nq = 0; nq < 4; ++nq) acc[m][nq] = (f32x4){0.f, 0.f, 0.f, 0.f};
  const float* xb = x + (size_t)b * NC * NN + (size_t)nt * 128;
  const char* Bp = fb + ((size_t)(b * 256 + ot * 128)) * 512;

  float4 f[8];   // A fp32 staging (two 4-row groups)

#define ALOADS(kt)                                                            \
  {                                                                           \
    _Pragma("unroll") for (int g = 0; g < 2; ++g)                             \
      _Pragma("unroll") for (int j = 0; j < 4; ++j)                           \
        f[g * 4 + j] = *(const float4*)&xb[(size_t)((kt) * 64 + c0 + g * 4 + j) * NN + n0]; \
  }
#define AWRITE(buf)                                                           \
  {                                                                           \
    _Pragma("unroll") for (int g = 0; g < 2; ++g)                             \
      _Pragma("unroll") for (int k = 0; k < 4; ++k) {                         \
        float v0 = ((const float*)&f[g * 4 + 0])[k];                          \
        float v1 = ((const float*)&f[g * 4 + 1])[k];                          \
        float v2 = ((const float*)&f[g * 4 + 2])[k];                          \
        float v3 = ((const float*)&f[g * 4 + 3])[k];                          \
        *(uint2*)&At[buf][(n0 + k) * 72 + c0 + g * 4] =                       \
            make_uint2(pk2(v0, v1), pk2(v2, v3));                             \
      }                                                                       \
  }

  // prologue: ktile 0 into buf 0
  stage_tile(Bp, 512, Bs[0], w, l);
  ALOADS(0); AWRITE(0);
  __syncthreads();

  for (int kt = 0; kt < 4; ++kt) {
    const int cur = kt & 1;
    if (kt < 3) {
      stage_tile(Bp + (kt + 1) * 128, 512, Bs[cur ^ 1], w, l);  // async, flies
      ALOADS(kt + 1);                                           // regs, fly
    }
    // ---- MFMA from buf cur ----
#pragma unroll
    for (int ks = 0; ks < 2; ++ks) {
      const int kb = ks * 64 + ((l >> 4) << 4);   // byte off in Bs rows
      const int ko = ks * 32 + ((l >> 4) << 3);   // elem off in At rows
      bf16x8 av[4], bv[4];
#pragma unroll
      for (int m = 0; m < 4; ++m) {
        int row = wm * 64 + m * 16 + (l & 15);
        av[m] = *(const bf16x8*)&At[cur][row * 72 + ko];
      }
#pragma unroll
      for (int nq = 0; nq < 4; ++nq) {
        int row = wn * 64 + nq * 16 + (l & 15);
        bv[nq] = *(const bf16x8*)(Bs[cur] + row * 128 + (kb ^ ((row & 7) << 4)));
      }
#pragma unroll
      for (int m = 0; m < 4; ++m)
#pragma unroll
        for (int nq = 0; nq < 4; ++nq)
          acc[m][nq] = __builtin_amdgcn_mfma_f32_16x16x32_bf16(
              av[m], bv[nq], acc[m][nq], 0, 0, 0);
    }
    if (kt < 3) {
      AWRITE(cur ^ 1);          // cvt waits vmcnt for ALOADS (hidden by MFMA)
      __syncthreads();          // publishes At/Bs[cur^1]; drains B prefetch
    }
  }
#undef ALOADS
#undef AWRITE
  // direct fragment stores: one float4 per fragment (r18, verified)
#pragma unroll
  for (int m = 0; m < 4; ++m)
#pragma unroll
    for (int nq = 0; nq < 4; ++nq) {
      int o = ot * 128 + wn * 64 + nq * 16 + (l & 15);
      int n = nt * 128 + wm * 64 + m * 16 + ((l >> 4) << 2);
      *(f32x4*)(out + ((size_t)(b * 256 + o)) * NN + n) = acc[m][nq];
    }
}

extern "C" void kernel_launch(void* const* d_in, const int* in_sizes, int n_in,
                              void* d_out, int out_size, void* d_ws, size_t ws_size,
                              hipStream_t stream) {
  const float* x     = (const float*)d_in[0];
  const float* wqkv  = (const float*)d_in[1];
  const float* wdwf  = (const float*)d_in[2];
  const float* temp  = (const float*)d_in[3];
  const float* wproj = (const float*)d_in[4];
  float* out = (float*)d_out;
  char* ws = (char*)d_ws;

  // Workspace layout (bytes); total ~45 MB
  unsigned short* gpart = (unsigned short*)ws;  // bf16 [32][B][256][256] 33,554,432
  float* G     = (float*)(ws + 33554432);       // f32 [B][256][256]    2,097,152
  float* T12   = (float*)(ws + 35651584);       // f32 [B][512][256]    4,194,304
  float* attn  = (float*)(ws + 39845888);       // f32 [B][256][256]    2,097,152
  char*  Fb    = ws + 41943040;                 // bf16 [B][256][256]   1,048,576
  float* Wcat  = (float*)(ws + 42991616);       // f32 [512][256]         524,288
  float* WkT   = (float*)(ws + 43515904);       // f32 [256][256]         262,144
  float* Wv2   = (float*)(ws + 43778048);       // f32 [256][256]         262,144
  float* nqk   = (float*)(ws + 44040192);       // f32 [B][512]            16,384

  // fused gram + weight-prep (320 blocks x 1024 threads)
  k_gramT<<<dim3(KS * NB + 64), dim3(1024), 0, stream>>>(
      x, gpart, wqkv, wdwf, Wcat, WkT, Wv2);
  k_reduceG<<<dim3(128, NB), dim3(256), 0, stream>>>(gpart, G);
  k_sgT<<<dim3(64, NB), dim3(256), 0, stream>>>(Wcat, G, T12, nqk);
  k_ssoft<<<dim3(32, NB), dim3(256), 0, stream>>>(T12, WkT, nqk, temp, attn);
  k_sg2x<<<dim3(32, NB), dim3(256), 0, stream>>>(wproj, attn, Wv2, Fb);
  k_final<<<dim3(128, 2, NB), dim3(256), 0, stream>>>(x, Fb, out);
}